// Round 2
// baseline (10240.984 us; speedup 1.0000x reference)
//
#include <hip/hip_runtime.h>
#include <math.h>
#include <stdint.h>

#define HW 16777216u
#define SMALL_CAP 16384u
#define BIG_CAP   (2u*1024u*1024u)   // round-0 level-1-bin collection, per side
#define LIST_CAP  (4u*1024u*1024u)   // round-1 candidate list, per side

// ---------------- threefry2x32 (JAX-compatible, 20 rounds) ----------------
__host__ __device__ inline uint32_t tf_rotl(uint32_t x, int n){ return (x<<n)|(x>>(32-n)); }

__host__ __device__ inline void threefry2x32(uint32_t k0, uint32_t k1, uint32_t x0, uint32_t x1,
                                             uint32_t &o0, uint32_t &o1){
  uint32_t ks2 = k0 ^ k1 ^ 0x1BD11BDAu;
  x0 += k0; x1 += k1;
#define TF_R4(a,b,c,d) \
  x0 += x1; x1 = tf_rotl(x1,(a)); x1 ^= x0; \
  x0 += x1; x1 = tf_rotl(x1,(b)); x1 ^= x0; \
  x0 += x1; x1 = tf_rotl(x1,(c)); x1 ^= x0; \
  x0 += x1; x1 = tf_rotl(x1,(d)); x1 ^= x0;
  TF_R4(13,15,26,6)  x0 += k1;  x1 += ks2 + 1u;
  TF_R4(17,29,16,24) x0 += ks2; x1 += k0  + 2u;
  TF_R4(13,15,26,6)  x0 += k0;  x1 += k1  + 3u;
  TF_R4(17,29,16,24) x0 += k1;  x1 += ks2 + 4u;
  TF_R4(13,15,26,6)  x0 += ks2; x1 += k0  + 5u;
#undef TF_R4
  o0 = x0; o1 = x1;
}

// order-preserving uint mapping for floats (ascending)
__device__ __forceinline__ uint32_t okey(float f){
  uint32_t b = __float_as_uint(f);
  return (b & 0x80000000u) ? ~b : (b | 0x80000000u);
}

// wave-aggregated append: one atomic per wave instead of per lane
__device__ __forceinline__ unsigned wave_reserve(unsigned* cnt){
  unsigned long long m = __ballot(1);
  unsigned lane = threadIdx.x & 63u;
  unsigned leader = (unsigned)__ffsll((unsigned long long)m) - 1u;
  unsigned prefix = (unsigned)__popcll(m & ((1ull << lane) - 1ull));
  unsigned base = 0u;
  if (lane == leader) base = atomicAdd(cnt, (unsigned)__popcll(m));
  base = __shfl(base, (int)leader, 64);
  return base + prefix;
}

// state layout (u32 indices into st):
// st[0]=sum(roi); per selection s at base B in {8:fg_cand,16:bg_cand,24:fg_score,32:bg_score}:
//   B+0 d1, B+1 rem1, B+2 d2, B+3 rem2, B+4 T(okey), B+5 cut_idx, B+6 rem3
// cnt: [0],[1] big/score list counts; [2],[3] small col counts; [4],[5] winner counts

// --------------- pass 1: roi sum + level-1 hists (zeros counted, not atomic'd)
__global__ void k_hist1(const float4* __restrict__ cam4, const int4* __restrict__ roi4,
                        unsigned* __restrict__ h1a, unsigned* __restrict__ h1b,
                        unsigned* __restrict__ st){
  __shared__ unsigned la[4096], lb[4096];
  __shared__ unsigned ssum;
  for (int j = threadIdx.x; j < 4096; j += blockDim.x){ la[j]=0u; lb[j]=0u; }
  if (threadIdx.x==0) ssum = 0u;
  __syncthreads();
  unsigned tid = blockIdx.x*blockDim.x + threadIdx.x;
  unsigned stride = gridDim.x*blockDim.x;      // must be 131072 (512x256)
  unsigned rs = 0u;
  for (unsigned u = tid; u < HW/4u; u += stride){
    float4 c = cam4[u]; int4 r = roi4[u];
#define H1(cc, rr) { unsigned ok = okey((cc) + 1e-8f); \
    if (rr){ atomicAdd(&la[ok>>20], 1u); rs++; } atomicAdd(&lb[ok>>20], 1u); }
    H1(c.x, r.x) H1(c.y, r.y) H1(c.z, r.z) H1(c.w, r.w)
#undef H1
  }
  atomicAdd(&ssum, rs);
  __syncthreads();
  for (int j = threadIdx.x; j < 4096; j += blockDim.x){
    unsigned va = la[j], vb = lb[j];
    if (va) atomicAdd(&h1a[j], va);
    if (vb) atomicAdd(&h1b[j], vb);
  }
  if (threadIdx.x==0){
    atomicAdd(&st[0], ssum);
    unsigned bin0 = okey(1e-8f) >> 20;         // all r==0 elements: vfg = 1e-8
    atomicAdd(&h1a[bin0], 32768u - ssum);      // each block handles exactly 32768 elems
  }
}

// --------------- block-cooperative select over 4096-bin hist --------------
__device__ void block_select4096(const unsigned* __restrict__ h, unsigned n, bool top,
                                 unsigned* out_bin, unsigned* out_rem){
  __shared__ unsigned csum[256];
  __shared__ unsigned sb, sr;
  unsigned t = threadIdx.x;
  unsigned s = 0u;
  #pragma unroll
  for (int j = 0; j < 16; j++) s += h[t*16 + j];
  csum[t] = s;
  __syncthreads();
  if (t == 0){
    unsigned rem = n; int c;
    if (top){ for (c = 255; c >= 0; c--){ if (csum[c] >= rem) break; rem -= csum[c]; } }
    else    { for (c = 0; c < 256; c++){ if (csum[c] >= rem) break; rem -= csum[c]; } }
    int b;
    if (top){ for (b = c*16+15; b > c*16; b--){ if (h[b] >= rem) break; rem -= h[b]; } }
    else    { for (b = c*16; b < c*16+15; b++){ if (h[b] >= rem) break; rem -= h[b]; } }
    sb = (unsigned)b; sr = rem;
  }
  __syncthreads();
  *out_bin = sb; *out_rem = sr;
  __syncthreads();
}

__global__ void k_fin1(const unsigned* __restrict__ h1a, const unsigned* __restrict__ h1b,
                       unsigned* __restrict__ st, int round){
  unsigned nA, nB; bool topA, topB; int bA, bB;
  if (round == 0){
    nA = (unsigned)(0.2f * (float)st[0]);  // trunc, f32 mult like jnp
    topA = true;  bA = 8;
    nB = 1677721u; topB = false; bB = 16;
  } else {
    nA = 5000u; nB = 5000u; topA = topB = true; bA = 24; bB = 32;
  }
  unsigned bin, rem;
  block_select4096(h1a, nA, topA, &bin, &rem);
  if (threadIdx.x==0){ st[bA+0]=bin; st[bA+1]=rem; }
  __syncthreads();
  block_select4096(h1b, nB, topB, &bin, &rem);
  if (threadIdx.x==0){ st[bB+0]=bin; st[bB+1]=rem; }
}

__global__ void k_fin2(const unsigned* __restrict__ h2a, const unsigned* __restrict__ h2b,
                       unsigned* __restrict__ st, int baseA, int baseB, int topA, int topB){
  unsigned bin, rem;
  block_select4096(h2a, st[baseA+1], topA!=0, &bin, &rem);
  if (threadIdx.x==0){ st[baseA+2]=bin; st[baseA+3]=rem; }
  __syncthreads();
  block_select4096(h2b, st[baseB+1], topB!=0, &bin, &rem);
  if (threadIdx.x==0){ st[baseB+2]=bin; st[baseB+3]=rem; }
}

// --------------- round 0: collect level-1-bin elements into big lists -----
__global__ void k_col12(const float4* __restrict__ cam4, const int4* __restrict__ roi4,
                        const unsigned* __restrict__ st,
                        unsigned long long* __restrict__ bigA,
                        unsigned long long* __restrict__ bigB,
                        unsigned* __restrict__ cnt){
  unsigned pa = st[8], pb = st[16];
  const unsigned OKEPS = okey(1e-8f);
  unsigned tid = blockIdx.x*blockDim.x + threadIdx.x;
  unsigned stride = gridDim.x*blockDim.x;
  for (unsigned u = tid; u < HW/4u; u += stride){
    float4 c = cam4[u]; int4 r = roi4[u];
#define C12(cc, rr, kk) { unsigned i = 4u*u + (kk); \
    unsigned okb = okey((cc) + 1e-8f); \
    unsigned okf = (rr) ? okb : OKEPS; \
    if ((okf>>20) == pa){ unsigned p = wave_reserve(&cnt[0]); \
      if (p < BIG_CAP) bigA[p] = ((unsigned long long)okf<<32) | i; } \
    if ((okb>>20) == pb){ unsigned p = wave_reserve(&cnt[1]); \
      if (p < BIG_CAP) bigB[p] = ((unsigned long long)okb<<32) | i; } }
    C12(c.x, r.x, 0u) C12(c.y, r.y, 1u) C12(c.z, r.z, 2u) C12(c.w, r.w, 3u)
#undef C12
  }
}

// --------------- generic: level-2 hist over (key<<32|idx) lists -----------
__global__ void k_list_hist2(const unsigned long long* __restrict__ LA,
                             const unsigned long long* __restrict__ LB,
                             const unsigned* __restrict__ cnt, const unsigned* __restrict__ st,
                             unsigned* __restrict__ h2a, unsigned* __restrict__ h2b,
                             int baseA, int baseB, unsigned capA, unsigned capB){
  __shared__ unsigned la[4096], lb[4096];
  for (int j = threadIdx.x; j < 4096; j += blockDim.x){ la[j]=0u; lb[j]=0u; }
  __syncthreads();
  unsigned pa = st[baseA], pb = st[baseB];
  unsigned mA = cnt[0] < capA ? cnt[0] : capA;
  unsigned mB = cnt[1] < capB ? cnt[1] : capB;
  unsigned tid = blockIdx.x*blockDim.x + threadIdx.x;
  unsigned stride = gridDim.x*blockDim.x;
  for (unsigned e = tid; e < mA; e += stride){
    unsigned key = (unsigned)(LA[e] >> 32);
    if ((key>>20) == pa) atomicAdd(&la[(key>>8)&0xFFFu], 1u);
  }
  for (unsigned e = tid; e < mB; e += stride){
    unsigned key = (unsigned)(LB[e] >> 32);
    if ((key>>20) == pb) atomicAdd(&lb[(key>>8)&0xFFFu], 1u);
  }
  __syncthreads();
  for (int j = threadIdx.x; j < 4096; j += blockDim.x){
    unsigned va = la[j], vb = lb[j];
    if (va) atomicAdd(&h2a[j], va);
    if (vb) atomicAdd(&h2b[j], vb);
  }
}

// --------------- generic: collect 24-bit-prefix matches to small col ------
__global__ void k_list_col(const unsigned long long* __restrict__ LA,
                           const unsigned long long* __restrict__ LB,
                           unsigned* __restrict__ cnt, const unsigned* __restrict__ st,
                           unsigned long long* __restrict__ colA,
                           unsigned long long* __restrict__ colB,
                           int baseA, int baseB, unsigned capA, unsigned capB){
  unsigned p24a = (st[baseA]<<12) | st[baseA+2];
  unsigned p24b = (st[baseB]<<12) | st[baseB+2];
  unsigned mA = cnt[0] < capA ? cnt[0] : capA;
  unsigned mB = cnt[1] < capB ? cnt[1] : capB;
  unsigned tid = blockIdx.x*blockDim.x + threadIdx.x;
  unsigned stride = gridDim.x*blockDim.x;
  for (unsigned e = tid; e < mA; e += stride){
    unsigned long long v = LA[e];
    unsigned key = (unsigned)(v >> 32);
    if ((key>>8) == p24a){
      unsigned p = wave_reserve(&cnt[2]);
      if (p < SMALL_CAP) colA[p] = ((unsigned long long)(key & 0xFFu) << 32) | (unsigned)v;
    }
  }
  for (unsigned e = tid; e < mB; e += stride){
    unsigned long long v = LB[e];
    unsigned key = (unsigned)(v >> 32);
    if ((key>>8) == p24b){
      unsigned p = wave_reserve(&cnt[3]);
      if (p < SMALL_CAP) colB[p] = ((unsigned long long)(key & 0xFFu) << 32) | (unsigned)v;
    }
  }
}

// --------------- finalize level 3: exact threshold + tie cutoff -----------
__global__ void k_fin3(const unsigned long long* __restrict__ colA,
                       const unsigned long long* __restrict__ colB,
                       const unsigned* __restrict__ cnt,
                       unsigned* __restrict__ st, int baseA, int baseB, int topA, int topB){
  __shared__ unsigned h[256];
  __shared__ unsigned s_d3, s_rem;
  for (int side = 0; side < 2; side++){
    int base = side ? baseB : baseA;
    bool top = side ? (topB!=0) : (topA!=0);
    const unsigned long long* col = side ? colB : colA;
    unsigned m = cnt[2+side]; if (m > SMALL_CAP) m = SMALL_CAP;
    unsigned n = st[base+3];  // rem2
    for (int j = threadIdx.x; j < 256; j += blockDim.x) h[j] = 0u;
    __syncthreads();
    for (unsigned e = threadIdx.x; e < m; e += blockDim.x)
      atomicAdd(&h[(unsigned)(col[e]>>32) & 0xFFu], 1u);
    __syncthreads();
    if (threadIdx.x == 0){
      unsigned rem = n; int b;
      if (top){ for (b = 255; b > 0; b--){ if (h[b] >= rem) break; rem -= h[b]; } }
      else    { for (b = 0; b < 255; b++){ if (h[b] >= rem) break; rem -= h[b]; } }
      s_d3 = (unsigned)b; s_rem = rem;
    }
    __syncthreads();
    unsigned d3 = s_d3, rem3 = s_rem;
    for (unsigned e = threadIdx.x; e < m; e += blockDim.x){
      unsigned long long v = col[e];
      if (((unsigned)(v>>32) & 0xFFu) == d3){
        unsigned idx = (unsigned)(v & 0xFFFFFFFFu);
        unsigned rank = 0;
        for (unsigned j = 0; j < m; j++){
          unsigned long long w = col[j];
          if (((unsigned)(w>>32) & 0xFFu) == d3 && (unsigned)(w & 0xFFFFFFFFu) < idx) rank++;
        }
        if (rank == rem3 - 1u){
          st[base+4] = (st[base+0]<<20) | (st[base+2]<<8) | d3;
          st[base+5] = idx;
          st[base+6] = rem3;
        }
      }
    }
    __syncthreads();
  }
}

// --------------- round 1a: candidacy map -> compact (prob,idx) lists ------
__global__ void k_cand_map(const float4* __restrict__ cam4, const int4* __restrict__ roi4,
                           const unsigned* __restrict__ st,
                           unsigned long long* __restrict__ LA,
                           unsigned long long* __restrict__ LB,
                           unsigned* __restrict__ cnt){
  unsigned Ta = st[12], ca = st[13];   // fg cand threshold okey + tie cutoff
  unsigned Tb = st[20], cb = st[21];   // bg cand
  const unsigned OKEPS = okey(1e-8f);
  unsigned tid = blockIdx.x*blockDim.x + threadIdx.x;
  unsigned stride = gridDim.x*blockDim.x;
  for (unsigned u = tid; u < HW/4u; u += stride){
    float4 c = cam4[u]; int4 r = roi4[u];
#define CM(cc, rr, kk) { unsigned i = 4u*u + (kk); \
    float vbg = (cc) + 1e-8f; \
    unsigned okb = okey(vbg); \
    unsigned okf = (rr) ? okb : OKEPS; \
    if (okf > Ta || (okf == Ta && i <= ca)){ \
      float prob = (rr) ? vbg : 1e-8f; \
      unsigned p = wave_reserve(&cnt[0]); \
      if (p < LIST_CAP) LA[p] = ((unsigned long long)__float_as_uint(prob)<<32) | i; } \
    if (okb < Tb || (okb == Tb && i <= cb)){ \
      float pb2 = fmaxf(1.0f - vbg, 0.0f) + 1e-8f; \
      unsigned p = wave_reserve(&cnt[1]); \
      if (p < LIST_CAP) LB[p] = ((unsigned long long)__float_as_uint(pb2)<<32) | i; } }
    CM(c.x, r.x, 0u) CM(c.y, r.y, 1u) CM(c.z, r.z, 2u) CM(c.w, r.w, 3u)
#undef CM
  }
}

// --------------- round 1b: dense gumbel over lists + level-1 hist ---------
__device__ __forceinline__ float gumbel_score(uint32_t kk0, uint32_t kk1, uint32_t i, float prob){
  uint32_t y0, y1; threefry2x32(kk0, kk1, 0u, i, y0, y1);
  uint32_t bits = y0 ^ y1;                       // partitionable 32-bit fold
  float f = __uint_as_float((bits>>9) | 0x3F800000u) - 1.0f;
  float u = fmaxf(1e-12f, f + 1e-12f);
  float l1 = (float)log((double)u);              // jnp.log(u)       (f32-rounded)
  float l2 = (float)log((double)(-l1));          // jnp.log(-log(u)) (f32-rounded)
  float lp = (float)log((double)prob);           // jnp.log(probs)   (f32-rounded)
  return lp - l2;
}

__global__ void k_gumbel(unsigned long long* __restrict__ LA,
                         unsigned long long* __restrict__ LB,
                         const unsigned* __restrict__ cnt,
                         unsigned* __restrict__ h1a, unsigned* __restrict__ h1b,
                         uint32_t kf0, uint32_t kf1, uint32_t kb0, uint32_t kb1){
  __shared__ unsigned la[4096], lb[4096];
  for (int j = threadIdx.x; j < 4096; j += blockDim.x){ la[j]=0u; lb[j]=0u; }
  __syncthreads();
  unsigned mA = cnt[0] < LIST_CAP ? cnt[0] : LIST_CAP;
  unsigned mB = cnt[1] < LIST_CAP ? cnt[1] : LIST_CAP;
  unsigned tid = blockIdx.x*blockDim.x + threadIdx.x;
  unsigned stride = gridDim.x*blockDim.x;
  for (unsigned e = tid; e < mA; e += stride){
    unsigned long long v = LA[e];
    unsigned i = (unsigned)v;
    float prob = __uint_as_float((unsigned)(v >> 32));
    unsigned key = okey(gumbel_score(kf0, kf1, i, prob));
    LA[e] = ((unsigned long long)key << 32) | i;
    atomicAdd(&la[key>>20], 1u);
  }
  for (unsigned e = tid; e < mB; e += stride){
    unsigned long long v = LB[e];
    unsigned i = (unsigned)v;
    float prob = __uint_as_float((unsigned)(v >> 32));
    unsigned key = okey(gumbel_score(kb0, kb1, i, prob));
    LB[e] = ((unsigned long long)key << 32) | i;
    atomicAdd(&lb[key>>20], 1u);
  }
  __syncthreads();
  for (int j = threadIdx.x; j < 4096; j += blockDim.x){
    unsigned va = la[j], vb = lb[j];
    if (va) atomicAdd(&h1a[j], va);
    if (vb) atomicAdd(&h1b[j], vb);
  }
}

// --------------- extract winner indices (exactly top-5000 per side) -------
__global__ void k_winners(const unsigned long long* __restrict__ LA,
                          const unsigned long long* __restrict__ LB,
                          unsigned* __restrict__ cnt, const unsigned* __restrict__ st,
                          unsigned* __restrict__ winA, unsigned* __restrict__ winB){
  unsigned Ta = st[28], ca = st[29];
  unsigned Tb = st[36], cb = st[37];
  unsigned mA = cnt[0] < LIST_CAP ? cnt[0] : LIST_CAP;
  unsigned mB = cnt[1] < LIST_CAP ? cnt[1] : LIST_CAP;
  unsigned tid = blockIdx.x*blockDim.x + threadIdx.x;
  unsigned stride = gridDim.x*blockDim.x;
  for (unsigned e = tid; e < mA; e += stride){
    unsigned long long v = LA[e];
    unsigned key = (unsigned)(v >> 32), i = (unsigned)v;
    if (key > Ta || (key == Ta && i <= ca)){
      unsigned p = wave_reserve(&cnt[4]);
      if (p < 8192u) winA[p] = i;
    }
  }
  for (unsigned e = tid; e < mB; e += stride){
    unsigned long long v = LB[e];
    unsigned key = (unsigned)(v >> 32), i = (unsigned)v;
    if (key > Tb || (key == Tb && i <= cb)){
      unsigned p = wave_reserve(&cnt[5]);
      if (p < 8192u) winB[p] = i;
    }
  }
}

__global__ void k_scatter(float* __restrict__ out,
                          const unsigned* __restrict__ winA, const unsigned* __restrict__ winB,
                          const unsigned* __restrict__ cnt){
  unsigned t = blockIdx.x*blockDim.x + threadIdx.x;
  unsigned nA = cnt[4] < 8192u ? cnt[4] : 8192u;
  unsigned nB = cnt[5] < 8192u ? cnt[5] : 8192u;
  if (t < nA) out[winA[t]] = 1.0f;
  if (t < nB) out[HW + winB[t]] = 1.0f;
}

extern "C" void kernel_launch(void* const* d_in, const int* in_sizes, int n_in,
                              void* d_out, int out_size, void* d_ws, size_t ws_size,
                              hipStream_t stream) {
  const float4* cam4 = (const float4*)d_in[0];
  const int4*   roi4 = (const int4*)d_in[1];
  float* out = (float*)d_out;

  uint8_t* w = (uint8_t*)d_ws;
  unsigned* h1a = (unsigned*)w;            // 4096 u32 @ 0
  unsigned* h1b = h1a + 4096;              // @16384
  unsigned* h2a = h1b + 4096;              // @32768
  unsigned* h2b = h2a + 4096;              // @49152
  unsigned* cnt = h2b + 4096;              // 16 u32 @ 65536
  unsigned* st  = cnt + 16;                // 64 u32 @ 65600
  unsigned long long* colA = (unsigned long long*)(w + 73728);            // 16384 u64
  unsigned long long* colB = colA + SMALL_CAP;                            // @204800
  unsigned* winA = (unsigned*)colA;        // reuse col region after fin3
  unsigned* winB = winA + 8192;

  // big/score lists live in d_out (scratch until final memset+scatter)
  unsigned long long* bigA = (unsigned long long*)d_out;                  // 16 MB
  unsigned long long* bigB = (unsigned long long*)((uint8_t*)d_out + (size_t)16*1024*1024);
  unsigned long long* LA   = (unsigned long long*)d_out;                  // 32 MB
  unsigned long long* LB   = (unsigned long long*)((uint8_t*)d_out + (size_t)32*1024*1024);

  // JAX: key(42) -> split -> k_fg, k_bg
  uint32_t kf0,kf1,kb0,kb1;
  threefry2x32(0u, 42u, 0u, 0u, kf0, kf1);
  threefry2x32(0u, 42u, 0u, 1u, kb0, kb1);

  // ---- round 0: candidate-set thresholds from cam order statistics ----
  hipMemsetAsync(d_ws, 0, 65856, stream);   // hists + cnt + st
  k_hist1<<<512, 256, 0, stream>>>(cam4, roi4, h1a, h1b, st);
  k_fin1<<<1, 256, 0, stream>>>(h1a, h1b, st, 0);
  k_col12<<<512, 256, 0, stream>>>(cam4, roi4, st, bigA, bigB, cnt);
  k_list_hist2<<<256, 256, 0, stream>>>(bigA, bigB, cnt, st, h2a, h2b, 8, 16, BIG_CAP, BIG_CAP);
  k_fin2<<<1, 256, 0, stream>>>(h2a, h2b, st, 8, 16, 1, 0);
  k_list_col<<<256, 256, 0, stream>>>(bigA, bigB, cnt, st, colA, colB, 8, 16, BIG_CAP, BIG_CAP);
  k_fin3<<<1, 256, 0, stream>>>(colA, colB, cnt, st, 8, 16, 1, 0);

  // ---- round 1: gumbel scores on candidates + top-5000 selection ----
  hipMemsetAsync(d_ws, 0, 65600, stream);   // hists + cnt (keep st)
  k_cand_map<<<512, 256, 0, stream>>>(cam4, roi4, st, LA, LB, cnt);
  k_gumbel<<<512, 256, 0, stream>>>(LA, LB, cnt, h1a, h1b, kf0, kf1, kb0, kb1);
  k_fin1<<<1, 256, 0, stream>>>(h1a, h1b, st, 1);
  k_list_hist2<<<256, 256, 0, stream>>>(LA, LB, cnt, st, h2a, h2b, 24, 32, LIST_CAP, LIST_CAP);
  k_fin2<<<1, 256, 0, stream>>>(h2a, h2b, st, 24, 32, 1, 1);
  k_list_col<<<256, 256, 0, stream>>>(LA, LB, cnt, st, colA, colB, 24, 32, LIST_CAP, LIST_CAP);
  k_fin3<<<1, 256, 0, stream>>>(colA, colB, cnt, st, 24, 32, 1, 1);
  k_winners<<<256, 256, 0, stream>>>(LA, LB, cnt, st, winA, winB);

  // ---- final: zero masks + scatter the 5000+5000 winners ----
  hipMemsetAsync(d_out, 0, (size_t)2*HW*4, stream);
  k_scatter<<<32, 256, 0, stream>>>(out, winA, winB, cnt);
}

// Round 3
// 619.241 us; speedup vs baseline: 16.5380x; 16.5380x over previous
//
#include <hip/hip_runtime.h>
#include <math.h>
#include <stdint.h>

#define HW 16777216u
#define SMALL_CAP 16384u
#define BIG_CAP   (2u*1024u*1024u)   // round-0 level-1-bin collection, per side
#define LIST_CAP  (4u*1024u*1024u)   // round-1 candidate list, per side

// ---------------- threefry2x32 (JAX-compatible, 20 rounds) ----------------
__host__ __device__ inline uint32_t tf_rotl(uint32_t x, int n){ return (x<<n)|(x>>(32-n)); }

__host__ __device__ inline void threefry2x32(uint32_t k0, uint32_t k1, uint32_t x0, uint32_t x1,
                                             uint32_t &o0, uint32_t &o1){
  uint32_t ks2 = k0 ^ k1 ^ 0x1BD11BDAu;
  x0 += k0; x1 += k1;
#define TF_R4(a,b,c,d) \
  x0 += x1; x1 = tf_rotl(x1,(a)); x1 ^= x0; \
  x0 += x1; x1 = tf_rotl(x1,(b)); x1 ^= x0; \
  x0 += x1; x1 = tf_rotl(x1,(c)); x1 ^= x0; \
  x0 += x1; x1 = tf_rotl(x1,(d)); x1 ^= x0;
  TF_R4(13,15,26,6)  x0 += k1;  x1 += ks2 + 1u;
  TF_R4(17,29,16,24) x0 += ks2; x1 += k0  + 2u;
  TF_R4(13,15,26,6)  x0 += k0;  x1 += k1  + 3u;
  TF_R4(17,29,16,24) x0 += k1;  x1 += ks2 + 4u;
  TF_R4(13,15,26,6)  x0 += ks2; x1 += k0  + 5u;
#undef TF_R4
  o0 = x0; o1 = x1;
}

// order-preserving uint mapping for floats (ascending)
__device__ __forceinline__ uint32_t okey(float f){
  uint32_t b = __float_as_uint(f);
  return (b & 0x80000000u) ? ~b : (b | 0x80000000u);
}

// block-wide 2-channel inclusive scan -> exclusive offsets + totals.
// ONE global atomic per block per channel replaces per-wave contended atomics
// (round-2 post-mortem: 524K same-address atomicAdd-with-return @ ~11ns each
//  serialized k_cand_map to 5.9ms with VALUBusy 0.4%).
__device__ void block_scan2(unsigned a, unsigned b, unsigned* offA, unsigned* offB,
                            unsigned* totA, unsigned* totB){
  __shared__ unsigned sA[256], sB[256];
  unsigned t = threadIdx.x;
  sA[t] = a; sB[t] = b;
  __syncthreads();
  for (int d = 1; d < 256; d <<= 1){
    unsigned xa = (t >= (unsigned)d) ? sA[t-d] : 0u;
    unsigned xb = (t >= (unsigned)d) ? sB[t-d] : 0u;
    __syncthreads();
    sA[t] += xa; sB[t] += xb;
    __syncthreads();
  }
  *offA = sA[t] - a; *offB = sB[t] - b;
  *totA = sA[255];   *totB = sB[255];
}

// state layout (u32 indices into st):
// st[0]=sum(roi); per selection at base B in {8:fg_cand,16:bg_cand,24:fg_score,32:bg_score}:
//   B+0 d1, B+1 rem1, B+2 d2, B+3 rem2, B+4 T(okey), B+5 cut_idx, B+6 rem3
// cnt: [0],[1] list counts; [2],[3] small col counts; [4],[5] winner counts

// --------------- pass 1: roi sum + level-1 hists --------------------------
__global__ void k_hist1(const float4* __restrict__ cam4, const int4* __restrict__ roi4,
                        unsigned* __restrict__ h1a, unsigned* __restrict__ h1b,
                        unsigned* __restrict__ st){
  __shared__ unsigned la[4096], lb[4096];
  __shared__ unsigned ssum;
  for (int j = threadIdx.x; j < 4096; j += blockDim.x){ la[j]=0u; lb[j]=0u; }
  if (threadIdx.x==0) ssum = 0u;
  __syncthreads();
  unsigned tid = blockIdx.x*blockDim.x + threadIdx.x;
  unsigned stride = gridDim.x*blockDim.x;      // 512x256: each block covers 32768 elems
  unsigned rs = 0u;
  for (unsigned u = tid; u < HW/4u; u += stride){
    float4 c = cam4[u]; int4 r = roi4[u];
#define H1(cc, rr) { unsigned ok = okey((cc) + 1e-8f); \
    if (rr){ atomicAdd(&la[ok>>20], 1u); rs++; } atomicAdd(&lb[ok>>20], 1u); }
    H1(c.x, r.x) H1(c.y, r.y) H1(c.z, r.z) H1(c.w, r.w)
#undef H1
  }
  atomicAdd(&ssum, rs);
  __syncthreads();
  for (int j = threadIdx.x; j < 4096; j += blockDim.x){
    unsigned va = la[j], vb = lb[j];
    if (va) atomicAdd(&h1a[j], va);
    if (vb) atomicAdd(&h1b[j], vb);
  }
  if (threadIdx.x==0){
    atomicAdd(&st[0], ssum);
    unsigned bin0 = okey(1e-8f) >> 20;         // all r==0 elements: vfg = 1e-8
    atomicAdd(&h1a[bin0], 32768u - ssum);
  }
}

// --------------- block-cooperative select over 4096-bin hist --------------
__device__ void block_select4096(const unsigned* __restrict__ h, unsigned n, bool top,
                                 unsigned* out_bin, unsigned* out_rem){
  __shared__ unsigned csum[256];
  __shared__ unsigned sb, sr;
  unsigned t = threadIdx.x;
  unsigned s = 0u;
  #pragma unroll
  for (int j = 0; j < 16; j++) s += h[t*16 + j];
  csum[t] = s;
  __syncthreads();
  if (t == 0){
    unsigned rem = n; int c;
    if (top){ for (c = 255; c >= 0; c--){ if (csum[c] >= rem) break; rem -= csum[c]; } }
    else    { for (c = 0; c < 256; c++){ if (csum[c] >= rem) break; rem -= csum[c]; } }
    int b;
    if (top){ for (b = c*16+15; b > c*16; b--){ if (h[b] >= rem) break; rem -= h[b]; } }
    else    { for (b = c*16; b < c*16+15; b++){ if (h[b] >= rem) break; rem -= h[b]; } }
    sb = (unsigned)b; sr = rem;
  }
  __syncthreads();
  *out_bin = sb; *out_rem = sr;
  __syncthreads();
}

__global__ void k_fin1(const unsigned* __restrict__ h1a, const unsigned* __restrict__ h1b,
                       unsigned* __restrict__ st, int round){
  unsigned nA, nB; bool topA, topB; int bA, bB;
  if (round == 0){
    nA = (unsigned)(0.2f * (float)st[0]);  // trunc, f32 mult like jnp
    topA = true;  bA = 8;
    nB = 1677721u; topB = false; bB = 16;
  } else {
    nA = 5000u; nB = 5000u; topA = topB = true; bA = 24; bB = 32;
  }
  unsigned bin, rem;
  block_select4096(h1a, nA, topA, &bin, &rem);
  if (threadIdx.x==0){ st[bA+0]=bin; st[bA+1]=rem; }
  __syncthreads();
  block_select4096(h1b, nB, topB, &bin, &rem);
  if (threadIdx.x==0){ st[bB+0]=bin; st[bB+1]=rem; }
}

__global__ void k_fin2(const unsigned* __restrict__ h2a, const unsigned* __restrict__ h2b,
                       unsigned* __restrict__ st, int baseA, int baseB, int topA, int topB){
  unsigned bin, rem;
  block_select4096(h2a, st[baseA+1], topA!=0, &bin, &rem);
  if (threadIdx.x==0){ st[baseA+2]=bin; st[baseA+3]=rem; }
  __syncthreads();
  block_select4096(h2b, st[baseB+1], topB!=0, &bin, &rem);
  if (threadIdx.x==0){ st[baseB+2]=bin; st[baseB+3]=rem; }
}

// --------------- round 0: collect level-1-bin elements (2-pass append) ----
__global__ void k_col12(const float4* __restrict__ cam4, const int4* __restrict__ roi4,
                        const unsigned* __restrict__ st,
                        unsigned long long* __restrict__ bigA,
                        unsigned long long* __restrict__ bigB,
                        unsigned* __restrict__ cnt){
  unsigned pa = st[8], pb = st[16];
  const unsigned OKEPS = okey(1e-8f);
  unsigned tid = blockIdx.x*blockDim.x + threadIdx.x;
  unsigned stride = gridDim.x*blockDim.x;
  unsigned hA = 0u, hB = 0u;
  for (unsigned u = tid; u < HW/4u; u += stride){
    float4 c = cam4[u]; int4 r = roi4[u];
#define CN(cc, rr) { unsigned okb = okey((cc) + 1e-8f); \
    unsigned okf = (rr) ? okb : OKEPS; \
    if ((okf>>20) == pa) hA++; \
    if ((okb>>20) == pb) hB++; }
    CN(c.x, r.x) CN(c.y, r.y) CN(c.z, r.z) CN(c.w, r.w)
#undef CN
  }
  unsigned offA, offB, totA, totB;
  block_scan2(hA, hB, &offA, &offB, &totA, &totB);
  __shared__ unsigned bA_s, bB_s;
  if (threadIdx.x==0){ bA_s = atomicAdd(&cnt[0], totA); bB_s = atomicAdd(&cnt[1], totB); }
  __syncthreads();
  unsigned pA = bA_s + offA, pB = bB_s + offB;
  for (unsigned u = tid; u < HW/4u; u += stride){
    float4 c = cam4[u]; int4 r = roi4[u];
#define CWv(cc, rr, kk) { unsigned i = 4u*u + (kk); \
    unsigned okb = okey((cc) + 1e-8f); \
    unsigned okf = (rr) ? okb : OKEPS; \
    if ((okf>>20) == pa){ if (pA < BIG_CAP) bigA[pA] = ((unsigned long long)okf<<32) | i; pA++; } \
    if ((okb>>20) == pb){ if (pB < BIG_CAP) bigB[pB] = ((unsigned long long)okb<<32) | i; pB++; } }
    CWv(c.x, r.x, 0u) CWv(c.y, r.y, 1u) CWv(c.z, r.z, 2u) CWv(c.w, r.w, 3u)
#undef CWv
  }
}

// --------------- generic: level-2 hist over (key<<32|idx) lists -----------
__global__ void k_list_hist2(const unsigned long long* __restrict__ LA,
                             const unsigned long long* __restrict__ LB,
                             const unsigned* __restrict__ cnt, const unsigned* __restrict__ st,
                             unsigned* __restrict__ h2a, unsigned* __restrict__ h2b,
                             int baseA, int baseB, unsigned capA, unsigned capB){
  __shared__ unsigned la[4096], lb[4096];
  for (int j = threadIdx.x; j < 4096; j += blockDim.x){ la[j]=0u; lb[j]=0u; }
  __syncthreads();
  unsigned pa = st[baseA], pb = st[baseB];
  unsigned mA = cnt[0] < capA ? cnt[0] : capA;
  unsigned mB = cnt[1] < capB ? cnt[1] : capB;
  unsigned tid = blockIdx.x*blockDim.x + threadIdx.x;
  unsigned stride = gridDim.x*blockDim.x;
  for (unsigned e = tid; e < mA; e += stride){
    unsigned key = (unsigned)(LA[e] >> 32);
    if ((key>>20) == pa) atomicAdd(&la[(key>>8)&0xFFFu], 1u);
  }
  for (unsigned e = tid; e < mB; e += stride){
    unsigned key = (unsigned)(LB[e] >> 32);
    if ((key>>20) == pb) atomicAdd(&lb[(key>>8)&0xFFFu], 1u);
  }
  __syncthreads();
  for (int j = threadIdx.x; j < 4096; j += blockDim.x){
    unsigned va = la[j], vb = lb[j];
    if (va) atomicAdd(&h2a[j], va);
    if (vb) atomicAdd(&h2b[j], vb);
  }
}

// --------------- generic: collect 24-bit-prefix matches (2-pass append) ---
__global__ void k_list_col(const unsigned long long* __restrict__ LA,
                           const unsigned long long* __restrict__ LB,
                           unsigned* __restrict__ cnt, const unsigned* __restrict__ st,
                           unsigned long long* __restrict__ colA,
                           unsigned long long* __restrict__ colB,
                           int baseA, int baseB, unsigned capA, unsigned capB){
  unsigned p24a = (st[baseA]<<12) | st[baseA+2];
  unsigned p24b = (st[baseB]<<12) | st[baseB+2];
  unsigned mA = cnt[0] < capA ? cnt[0] : capA;
  unsigned mB = cnt[1] < capB ? cnt[1] : capB;
  unsigned tid = blockIdx.x*blockDim.x + threadIdx.x;
  unsigned stride = gridDim.x*blockDim.x;
  unsigned hA = 0u, hB = 0u;
  for (unsigned e = tid; e < mA; e += stride)
    if (((unsigned)(LA[e]>>32)>>8) == p24a) hA++;
  for (unsigned e = tid; e < mB; e += stride)
    if (((unsigned)(LB[e]>>32)>>8) == p24b) hB++;
  unsigned offA, offB, totA, totB;
  block_scan2(hA, hB, &offA, &offB, &totA, &totB);
  __shared__ unsigned bA_s, bB_s;
  if (threadIdx.x==0){ bA_s = atomicAdd(&cnt[2], totA); bB_s = atomicAdd(&cnt[3], totB); }
  __syncthreads();
  unsigned pA = bA_s + offA, pB = bB_s + offB;
  for (unsigned e = tid; e < mA; e += stride){
    unsigned long long v = LA[e];
    unsigned key = (unsigned)(v >> 32);
    if ((key>>8) == p24a){
      if (pA < SMALL_CAP) colA[pA] = ((unsigned long long)(key & 0xFFu) << 32) | (unsigned)v;
      pA++;
    }
  }
  for (unsigned e = tid; e < mB; e += stride){
    unsigned long long v = LB[e];
    unsigned key = (unsigned)(v >> 32);
    if ((key>>8) == p24b){
      if (pB < SMALL_CAP) colB[pB] = ((unsigned long long)(key & 0xFFu) << 32) | (unsigned)v;
      pB++;
    }
  }
}

// --------------- finalize level 3: exact threshold + tie cutoff -----------
__global__ void k_fin3(const unsigned long long* __restrict__ colA,
                       const unsigned long long* __restrict__ colB,
                       const unsigned* __restrict__ cnt,
                       unsigned* __restrict__ st, int baseA, int baseB, int topA, int topB){
  __shared__ unsigned h[256];
  __shared__ unsigned s_d3, s_rem;
  for (int side = 0; side < 2; side++){
    int base = side ? baseB : baseA;
    bool top = side ? (topB!=0) : (topA!=0);
    const unsigned long long* col = side ? colB : colA;
    unsigned m = cnt[2+side]; if (m > SMALL_CAP) m = SMALL_CAP;
    unsigned n = st[base+3];  // rem2
    for (int j = threadIdx.x; j < 256; j += blockDim.x) h[j] = 0u;
    __syncthreads();
    for (unsigned e = threadIdx.x; e < m; e += blockDim.x)
      atomicAdd(&h[(unsigned)(col[e]>>32) & 0xFFu], 1u);
    __syncthreads();
    if (threadIdx.x == 0){
      unsigned rem = n; int b;
      if (top){ for (b = 255; b > 0; b--){ if (h[b] >= rem) break; rem -= h[b]; } }
      else    { for (b = 0; b < 255; b++){ if (h[b] >= rem) break; rem -= h[b]; } }
      s_d3 = (unsigned)b; s_rem = rem;
    }
    __syncthreads();
    unsigned d3 = s_d3, rem3 = s_rem;
    for (unsigned e = threadIdx.x; e < m; e += blockDim.x){
      unsigned long long v = col[e];
      if (((unsigned)(v>>32) & 0xFFu) == d3){
        unsigned idx = (unsigned)(v & 0xFFFFFFFFu);
        unsigned rank = 0;
        for (unsigned j = 0; j < m; j++){
          unsigned long long w = col[j];
          if (((unsigned)(w>>32) & 0xFFu) == d3 && (unsigned)(w & 0xFFFFFFFFu) < idx) rank++;
        }
        if (rank == rem3 - 1u){
          st[base+4] = (st[base+0]<<20) | (st[base+2]<<8) | d3;
          st[base+5] = idx;
          st[base+6] = rem3;
        }
      }
    }
    __syncthreads();
  }
}

// --------------- round 1a: candidacy map -> compact (prob,idx) lists ------
__global__ void k_cand_map(const float4* __restrict__ cam4, const int4* __restrict__ roi4,
                           const unsigned* __restrict__ st,
                           unsigned long long* __restrict__ LA,
                           unsigned long long* __restrict__ LB,
                           unsigned* __restrict__ cnt){
  unsigned Ta = st[12], ca = st[13];   // fg cand threshold okey + tie cutoff
  unsigned Tb = st[20], cb = st[21];   // bg cand
  const unsigned OKEPS = okey(1e-8f);
  unsigned tid = blockIdx.x*blockDim.x + threadIdx.x;
  unsigned stride = gridDim.x*blockDim.x;
  unsigned hA = 0u, hB = 0u;
  for (unsigned u = tid; u < HW/4u; u += stride){
    float4 c = cam4[u]; int4 r = roi4[u];
#define CM(cc, rr, kk) { unsigned i = 4u*u + (kk); \
    unsigned okb = okey((cc) + 1e-8f); \
    unsigned okf = (rr) ? okb : OKEPS; \
    if (okf > Ta || (okf == Ta && i <= ca)) hA++; \
    if (okb < Tb || (okb == Tb && i <= cb)) hB++; }
    CM(c.x, r.x, 0u) CM(c.y, r.y, 1u) CM(c.z, r.z, 2u) CM(c.w, r.w, 3u)
#undef CM
  }
  unsigned offA, offB, totA, totB;
  block_scan2(hA, hB, &offA, &offB, &totA, &totB);
  __shared__ unsigned bA_s, bB_s;
  if (threadIdx.x==0){ bA_s = atomicAdd(&cnt[0], totA); bB_s = atomicAdd(&cnt[1], totB); }
  __syncthreads();
  unsigned pA = bA_s + offA, pB = bB_s + offB;
  for (unsigned u = tid; u < HW/4u; u += stride){
    float4 c = cam4[u]; int4 r = roi4[u];
#define CW(cc, rr, kk) { unsigned i = 4u*u + (kk); \
    float vbg = (cc) + 1e-8f; \
    unsigned okb = okey(vbg); \
    unsigned okf = (rr) ? okb : OKEPS; \
    if (okf > Ta || (okf == Ta && i <= ca)){ \
      float prob = (rr) ? vbg : 1e-8f; \
      if (pA < LIST_CAP) LA[pA] = ((unsigned long long)__float_as_uint(prob)<<32) | i; pA++; } \
    if (okb < Tb || (okb == Tb && i <= cb)){ \
      float pb2 = fmaxf(1.0f - vbg, 0.0f) + 1e-8f; \
      if (pB < LIST_CAP) LB[pB] = ((unsigned long long)__float_as_uint(pb2)<<32) | i; pB++; } }
    CW(c.x, r.x, 0u) CW(c.y, r.y, 1u) CW(c.z, r.z, 2u) CW(c.w, r.w, 3u)
#undef CW
  }
}

// --------------- round 1b: dense gumbel over lists + level-1 hist ---------
__device__ __forceinline__ float gumbel_score(uint32_t kk0, uint32_t kk1, uint32_t i, float prob){
  uint32_t y0, y1; threefry2x32(kk0, kk1, 0u, i, y0, y1);
  uint32_t bits = y0 ^ y1;                       // partitionable 32-bit fold
  float f = __uint_as_float((bits>>9) | 0x3F800000u) - 1.0f;
  float u = fmaxf(1e-12f, f + 1e-12f);
  float l1 = (float)log((double)u);              // jnp.log(u)       (f32-rounded)
  float l2 = (float)log((double)(-l1));          // jnp.log(-log(u)) (f32-rounded)
  float lp = (float)log((double)prob);           // jnp.log(probs)   (f32-rounded)
  return lp - l2;
}

__global__ void k_gumbel(unsigned long long* __restrict__ LA,
                         unsigned long long* __restrict__ LB,
                         const unsigned* __restrict__ cnt,
                         unsigned* __restrict__ h1a, unsigned* __restrict__ h1b,
                         uint32_t kf0, uint32_t kf1, uint32_t kb0, uint32_t kb1){
  __shared__ unsigned la[4096], lb[4096];
  for (int j = threadIdx.x; j < 4096; j += blockDim.x){ la[j]=0u; lb[j]=0u; }
  __syncthreads();
  unsigned mA = cnt[0] < LIST_CAP ? cnt[0] : LIST_CAP;
  unsigned mB = cnt[1] < LIST_CAP ? cnt[1] : LIST_CAP;
  unsigned tid = blockIdx.x*blockDim.x + threadIdx.x;
  unsigned stride = gridDim.x*blockDim.x;
  for (unsigned e = tid; e < mA; e += stride){
    unsigned long long v = LA[e];
    unsigned i = (unsigned)v;
    float prob = __uint_as_float((unsigned)(v >> 32));
    unsigned key = okey(gumbel_score(kf0, kf1, i, prob));
    LA[e] = ((unsigned long long)key << 32) | i;
    atomicAdd(&la[key>>20], 1u);
  }
  for (unsigned e = tid; e < mB; e += stride){
    unsigned long long v = LB[e];
    unsigned i = (unsigned)v;
    float prob = __uint_as_float((unsigned)(v >> 32));
    unsigned key = okey(gumbel_score(kb0, kb1, i, prob));
    LB[e] = ((unsigned long long)key << 32) | i;
    atomicAdd(&lb[key>>20], 1u);
  }
  __syncthreads();
  for (int j = threadIdx.x; j < 4096; j += blockDim.x){
    unsigned va = la[j], vb = lb[j];
    if (va) atomicAdd(&h1a[j], va);
    if (vb) atomicAdd(&h1b[j], vb);
  }
}

// --------------- extract winner indices (2-pass append) -------------------
__global__ void k_winners(const unsigned long long* __restrict__ LA,
                          const unsigned long long* __restrict__ LB,
                          unsigned* __restrict__ cnt, const unsigned* __restrict__ st,
                          unsigned* __restrict__ winA, unsigned* __restrict__ winB){
  unsigned Ta = st[28], ca = st[29];
  unsigned Tb = st[36], cb = st[37];
  unsigned mA = cnt[0] < LIST_CAP ? cnt[0] : LIST_CAP;
  unsigned mB = cnt[1] < LIST_CAP ? cnt[1] : LIST_CAP;
  unsigned tid = blockIdx.x*blockDim.x + threadIdx.x;
  unsigned stride = gridDim.x*blockDim.x;
  unsigned hA = 0u, hB = 0u;
  for (unsigned e = tid; e < mA; e += stride){
    unsigned long long v = LA[e];
    unsigned key = (unsigned)(v >> 32), i = (unsigned)v;
    if (key > Ta || (key == Ta && i <= ca)) hA++;
  }
  for (unsigned e = tid; e < mB; e += stride){
    unsigned long long v = LB[e];
    unsigned key = (unsigned)(v >> 32), i = (unsigned)v;
    if (key > Tb || (key == Tb && i <= cb)) hB++;
  }
  unsigned offA, offB, totA, totB;
  block_scan2(hA, hB, &offA, &offB, &totA, &totB);
  __shared__ unsigned bA_s, bB_s;
  if (threadIdx.x==0){ bA_s = atomicAdd(&cnt[4], totA); bB_s = atomicAdd(&cnt[5], totB); }
  __syncthreads();
  unsigned pA = bA_s + offA, pB = bB_s + offB;
  for (unsigned e = tid; e < mA; e += stride){
    unsigned long long v = LA[e];
    unsigned key = (unsigned)(v >> 32), i = (unsigned)v;
    if (key > Ta || (key == Ta && i <= ca)){ if (pA < 8192u) winA[pA] = i; pA++; }
  }
  for (unsigned e = tid; e < mB; e += stride){
    unsigned long long v = LB[e];
    unsigned key = (unsigned)(v >> 32), i = (unsigned)v;
    if (key > Tb || (key == Tb && i <= cb)){ if (pB < 8192u) winB[pB] = i; pB++; }
  }
}

__global__ void k_scatter(float* __restrict__ out,
                          const unsigned* __restrict__ winA, const unsigned* __restrict__ winB,
                          const unsigned* __restrict__ cnt){
  unsigned t = blockIdx.x*blockDim.x + threadIdx.x;
  unsigned nA = cnt[4] < 8192u ? cnt[4] : 8192u;
  unsigned nB = cnt[5] < 8192u ? cnt[5] : 8192u;
  if (t < nA) out[winA[t]] = 1.0f;
  if (t < nB) out[HW + winB[t]] = 1.0f;
}

extern "C" void kernel_launch(void* const* d_in, const int* in_sizes, int n_in,
                              void* d_out, int out_size, void* d_ws, size_t ws_size,
                              hipStream_t stream) {
  const float4* cam4 = (const float4*)d_in[0];
  const int4*   roi4 = (const int4*)d_in[1];
  float* out = (float*)d_out;

  uint8_t* w = (uint8_t*)d_ws;
  unsigned* h1a = (unsigned*)w;            // 4096 u32 @ 0
  unsigned* h1b = h1a + 4096;              // @16384
  unsigned* h2a = h1b + 4096;              // @32768
  unsigned* h2b = h2a + 4096;              // @49152
  unsigned* cnt = h2b + 4096;              // 16 u32 @ 65536
  unsigned* st  = cnt + 16;                // 64 u32 @ 65600
  unsigned long long* colA = (unsigned long long*)(w + 73728);            // 16384 u64
  unsigned long long* colB = colA + SMALL_CAP;
  unsigned* winA = (unsigned*)colA;        // reuse col region after fin3
  unsigned* winB = winA + 8192;

  // big/score lists live in d_out (scratch until final memset+scatter)
  unsigned long long* bigA = (unsigned long long*)d_out;                  // [0,16MB)
  unsigned long long* bigB = (unsigned long long*)((uint8_t*)d_out + (size_t)16*1024*1024);
  unsigned long long* LA   = (unsigned long long*)d_out;                  // [0,32MB)
  unsigned long long* LB   = (unsigned long long*)((uint8_t*)d_out + (size_t)32*1024*1024);

  // JAX: key(42) -> split -> k_fg, k_bg
  uint32_t kf0,kf1,kb0,kb1;
  threefry2x32(0u, 42u, 0u, 0u, kf0, kf1);
  threefry2x32(0u, 42u, 0u, 1u, kb0, kb1);

  // ---- round 0: candidate-set thresholds from cam order statistics ----
  hipMemsetAsync(d_ws, 0, 65856, stream);   // hists + cnt + st
  k_hist1<<<512, 256, 0, stream>>>(cam4, roi4, h1a, h1b, st);
  k_fin1<<<1, 256, 0, stream>>>(h1a, h1b, st, 0);
  k_col12<<<512, 256, 0, stream>>>(cam4, roi4, st, bigA, bigB, cnt);
  k_list_hist2<<<256, 256, 0, stream>>>(bigA, bigB, cnt, st, h2a, h2b, 8, 16, BIG_CAP, BIG_CAP);
  k_fin2<<<1, 256, 0, stream>>>(h2a, h2b, st, 8, 16, 1, 0);
  k_list_col<<<256, 256, 0, stream>>>(bigA, bigB, cnt, st, colA, colB, 8, 16, BIG_CAP, BIG_CAP);
  k_fin3<<<1, 256, 0, stream>>>(colA, colB, cnt, st, 8, 16, 1, 0);

  // ---- round 1: gumbel scores on candidates + top-5000 selection ----
  hipMemsetAsync(d_ws, 0, 65600, stream);   // hists + cnt (keep st)
  k_cand_map<<<512, 256, 0, stream>>>(cam4, roi4, st, LA, LB, cnt);
  k_gumbel<<<512, 256, 0, stream>>>(LA, LB, cnt, h1a, h1b, kf0, kf1, kb0, kb1);
  k_fin1<<<1, 256, 0, stream>>>(h1a, h1b, st, 1);
  k_list_hist2<<<256, 256, 0, stream>>>(LA, LB, cnt, st, h2a, h2b, 24, 32, LIST_CAP, LIST_CAP);
  k_fin2<<<1, 256, 0, stream>>>(h2a, h2b, st, 24, 32, 1, 1);
  k_list_col<<<256, 256, 0, stream>>>(LA, LB, cnt, st, colA, colB, 24, 32, LIST_CAP, LIST_CAP);
  k_fin3<<<1, 256, 0, stream>>>(colA, colB, cnt, st, 24, 32, 1, 1);
  k_winners<<<256, 256, 0, stream>>>(LA, LB, cnt, st, winA, winB);

  // ---- final: zero masks + scatter the 5000+5000 winners ----
  hipMemsetAsync(d_out, 0, (size_t)2*HW*4, stream);
  k_scatter<<<32, 256, 0, stream>>>(out, winA, winB, cnt);
}